// Round 5
// baseline (1549.714 us; speedup 1.0000x reference)
//
#include <hip/hip_runtime.h>
#include <math.h>

#define Bx   8
#define Nx   5000
#define Kx   16
#define DINx 128
#define Hx   128
#define G4x  512
#define Mx   40000

typedef __attribute__((ext_vector_type(8))) short sh8;   // 8 bf16 (4 VGPR)
typedef __attribute__((ext_vector_type(4))) float f32x4; // MFMA acc

__device__ __forceinline__ float sigf(float v) {
    return __fdividef(1.0f, 1.0f + __expf(-v));
}
__device__ __forceinline__ float tanf_(float v) {
    return 1.0f - __fdividef(2.0f, __expf(2.0f * v) + 1.0f);
}
__device__ __forceinline__ unsigned short rne16(float f) {
    unsigned int u = __float_as_uint(f);
    return (unsigned short)((u + 0x7fffu + ((u >> 16) & 1u)) >> 16);
}
__device__ __forceinline__ float b2f(unsigned short s) {
    return __uint_as_float(((unsigned int)s) << 16);
}

#define FMA4(P, A, Q)                                        \
    P = fmaf((A).x, (Q).x, P); P = fmaf((A).y, (Q).y, P);    \
    P = fmaf((A).z, (Q).z, P); P = fmaf((A).w, (Q).w, P);

// ---------------------------------------------------------------------------
// Kernel A: G[m][0:512] = W_ih @ x[m];  S[m] = W_self@x[m]+b_self
// 16 rows/block (halves W_ih re-fetch vs 8), 128 thr, 5 cols/thread.
// ---------------------------------------------------------------------------
__global__ __launch_bounds__(128) void ka(const float* __restrict__ x,
        const float* __restrict__ W_ih, const float* __restrict__ W_self,
        const float* __restrict__ b_self, float* __restrict__ G,
        float* __restrict__ S)
{
    __shared__ float xs[16 * DINx];
    const int m0 = blockIdx.x * 16;
    {
        const float4* src = (const float4*)(x + (size_t)m0 * DINx);
        float4* dst = (float4*)xs;
        #pragma unroll
        for (int i = 0; i < 4; ++i)
            dst[threadIdx.x + 128 * i] = src[threadIdx.x + 128 * i];
    }
    __syncthreads();

    const int t = threadIdx.x;
    const float4* wp[5];
    #pragma unroll
    for (int c = 0; c < 5; ++c) {
        const int o = t + 128 * c;
        wp[c] = (const float4*)((o < G4x) ? (W_ih + (size_t)o * DINx)
                                          : (W_self + (size_t)(o - G4x) * DINx));
    }
    float acc[16][5];
    #pragma unroll
    for (int n = 0; n < 16; ++n)
        #pragma unroll
        for (int c = 0; c < 5; ++c) acc[n][c] = 0.f;

    #pragma unroll 2
    for (int k4 = 0; k4 < 32; ++k4) {
        float4 wv[5];
        #pragma unroll
        for (int c = 0; c < 5; ++c) wv[c] = wp[c][k4];
        #pragma unroll
        for (int n = 0; n < 16; ++n) {
            const float4 xv = ((const float4*)(xs + n * DINx))[k4];
            #pragma unroll
            for (int c = 0; c < 5; ++c) { FMA4(acc[n][c], xv, wv[c]); }
        }
    }
    const float bs = b_self[t];
    #pragma unroll
    for (int n = 0; n < 16; ++n) {
        const size_t m = (size_t)(m0 + n);
        #pragma unroll
        for (int c = 0; c < 4; ++c)
            G[m * G4x + t + 128 * c] = acc[n][c];
        S[m * Hx + t] = acc[n][4] + bs;
    }
}

// ---------------------------------------------------------------------------
// Kernel W: split W_hh into bf16 hi + residual lo, PACKED into per-wave
// contiguous MFMA A-fragments: pidx(dg16,kt,lane,e) so a wave's (g,dt,kt)
// fragment is one contiguous 1KB chunk (lane-linear, 16B/lane).
// Also bsum = b_ih + b_hh.
// ---------------------------------------------------------------------------
__global__ __launch_bounds__(256) void kw(const float* __restrict__ W_hh,
        const float* __restrict__ b_ih, const float* __restrict__ b_hh,
        unsigned short* __restrict__ WHp, unsigned short* __restrict__ WLp,
        float* __restrict__ bsum)
{
    const int i = blockIdx.x * 256 + threadIdx.x;
    if (i < G4x * Hx) {
        const int gdim = i >> 7, kcol = i & 127;
        const float w = W_hh[i];
        const unsigned short hi = rne16(w);
        const unsigned short lo = rne16(w - b2f(hi));
        const int dg16 = gdim >> 4, r16 = gdim & 15;
        const int kt = kcol >> 5, quad = (kcol >> 3) & 3, e = kcol & 7;
        const int pidx = (((dg16 * 4 + kt) * 64) + quad * 16 + r16) * 8 + e;
        WHp[pidx] = hi;
        WLp[pidx] = lo;
    }
    if (i < G4x) bsum[i] = b_ih[i] + b_hh[i];
}

// ---------------------------------------------------------------------------
// Kernel B: LSTM recurrence, transposed MFMA D = W_slice · h^T.
// 256 thr (4 waves), 32 seqs/block. Wave v owns dims v*32..+32 of all gates.
// Thread owns (dims quad*4..+4, seq row16) per (st,dt) -> float4 gathers.
// acc initialized to wk*gather+bias BEFORE MFMA (C-input accumulation) ->
// tiny gather live-range, VGPR under the (256,3) bound. W from packed L2
// stream; h in LDS bf16 hi/lo with 16B-granule XOR swizzle; hsF aliased.
// ---------------------------------------------------------------------------
__global__ __launch_bounds__(256, 3) void kb(const float* __restrict__ G,
        const float* __restrict__ S, const unsigned short* __restrict__ WHp,
        const unsigned short* __restrict__ WLp, const float* __restrict__ bsum,
        const int* __restrict__ nidx, const float* __restrict__ nw,
        const float* __restrict__ W_comb, const float* __restrict__ b_comb,
        float* __restrict__ out)
{
    // smem: [0,8192) hsHI u16[32][128]; [8192,16384) hsLO;
    //       hsF f32[32][136] ALIASES [0,17408) (used only after last step);
    //       [17408,+2048) gofs; [+2048) wts; [+2048) biasL. total 23552 B.
    __shared__ __align__(16) char smem[23552];
    unsigned short* hsHI = (unsigned short*)smem;
    unsigned short* hsLO = (unsigned short*)(smem + 8192);
    float*          hsF  = (float*)smem;
    int*            gofs = (int*)(smem + 17408);
    float*          wts  = (float*)(smem + 17408 + 2048);
    float*          biasL= (float*)(smem + 17408 + 4096);

    const int tid   = threadIdx.x;
    const int lane  = tid & 63;
    const int v     = tid >> 6;         // wave 0..3
    const int row16 = lane & 15;        // = seq within 16-tile (B col / D col)
    const int quad  = lane >> 4;        // 0..3
    const int kk    = row16 & 7;        // swizzle key (same for both st-tiles)
    const int dimb  = v * 32;
    const int m0    = blockIdx.x * 32;

    for (int i = tid; i < 512; i += 256) {
        const int s = i & 31, kstep = i >> 5;
        const int m = m0 + s;
        const int bb = m / Nx;
        const int nn = m - bb * Nx;
        gofs[kstep * 32 + s] = (bb * Nx + nidx[nn * Kx + kstep]) * G4x;
        wts [kstep * 32 + s] = nw[nn * Kx + kstep];
    }
    biasL[tid]       = bsum[tid];
    biasL[tid + 256] = bsum[tid + 256];

    float cst[2][2][4];
    #pragma unroll
    for (int st = 0; st < 2; ++st)
        #pragma unroll
        for (int dt = 0; dt < 2; ++dt)
            #pragma unroll
            for (int j = 0; j < 4; ++j) cst[st][dt][j] = 0.f;

    __syncthreads();

    #pragma unroll 1
    for (int k = 0; k < Kx; ++k) {
        const float wk0 = wts[k * 32 + row16];
        const float wk1 = wts[k * 32 + 16 + row16];
        const float* g0p = G + gofs[k * 32 + row16] + dimb + quad * 4;
        const float* g1p = G + gofs[k * 32 + 16 + row16] + dimb + quad * 4;

        // acc = wk * gathered_G + bias  (MFMA accumulates on top)
        f32x4 acc[4][2][2];
        #pragma unroll
        for (int g = 0; g < 4; ++g)
            #pragma unroll
            for (int dt = 0; dt < 2; ++dt) {
                const int off = (g << 7) + (dt << 4);
                const float4 bz = *(const float4*)(biasL + off + dimb + quad * 4);
                const float4 v0 = *(const float4*)(g0p + off);
                const float4 v1 = *(const float4*)(g1p + off);
                acc[g][dt][0][0] = fmaf(wk0, v0.x, bz.x);
                acc[g][dt][0][1] = fmaf(wk0, v0.y, bz.y);
                acc[g][dt][0][2] = fmaf(wk0, v0.z, bz.z);
                acc[g][dt][0][3] = fmaf(wk0, v0.w, bz.w);
                acc[g][dt][1][0] = fmaf(wk1, v1.x, bz.x);
                acc[g][dt][1][1] = fmaf(wk1, v1.y, bz.y);
                acc[g][dt][1][2] = fmaf(wk1, v1.z, bz.z);
                acc[g][dt][1][3] = fmaf(wk1, v1.w, bz.w);
            }

        if (k) {  // h == 0 at k == 0
            #pragma unroll
            for (int kt = 0; kt < 4; ++kt) {
                const int rsw = (kt * 4 + quad) ^ kk;
                const sh8 bhi0 = ((const sh8*)hsHI)[row16 * 16 + rsw];
                const sh8 blo0 = ((const sh8*)hsLO)[row16 * 16 + rsw];
                const sh8 bhi1 = ((const sh8*)hsHI)[(16 + row16) * 16 + rsw];
                const sh8 blo1 = ((const sh8*)hsLO)[(16 + row16) * 16 + rsw];
                #pragma unroll
                for (int g = 0; g < 4; ++g)
                    #pragma unroll
                    for (int dt = 0; dt < 2; ++dt) {
                        const int wi = ((g * 8 + v * 2 + dt) * 4 + kt) * 64 + lane;
                        const sh8 wh = ((const sh8*)WHp)[wi];
                        const sh8 wl = ((const sh8*)WLp)[wi];
                        acc[g][dt][0] = __builtin_amdgcn_mfma_f32_16x16x32_bf16(
                            wh, bhi0, acc[g][dt][0], 0, 0, 0);
                        acc[g][dt][0] = __builtin_amdgcn_mfma_f32_16x16x32_bf16(
                            wh, blo0, acc[g][dt][0], 0, 0, 0);
                        acc[g][dt][0] = __builtin_amdgcn_mfma_f32_16x16x32_bf16(
                            wl, bhi0, acc[g][dt][0], 0, 0, 0);
                        acc[g][dt][1] = __builtin_amdgcn_mfma_f32_16x16x32_bf16(
                            wh, bhi1, acc[g][dt][1], 0, 0, 0);
                        acc[g][dt][1] = __builtin_amdgcn_mfma_f32_16x16x32_bf16(
                            wh, blo1, acc[g][dt][1], 0, 0, 0);
                        acc[g][dt][1] = __builtin_amdgcn_mfma_f32_16x16x32_bf16(
                            wl, bhi1, acc[g][dt][1], 0, 0, 0);
                    }
            }
        }

        // ---- activations: i,f,g,o -> c,h (registers only) ----
        float hv[2][2][4];
        #pragma unroll
        for (int st = 0; st < 2; ++st)
            #pragma unroll
            for (int dt = 0; dt < 2; ++dt)
                #pragma unroll
                for (int j = 0; j < 4; ++j) {
                    const float ig = sigf(acc[0][dt][st][j]);
                    const float fg = sigf(acc[1][dt][st][j]);
                    const float gg = tanf_(acc[2][dt][st][j]);
                    const float og = sigf(acc[3][dt][st][j]);
                    const float cc = fg * cst[st][dt][j] + ig * gg;
                    cst[st][dt][j] = cc;
                    hv[st][dt][j] = og * tanf_(cc);
                }

        __syncthreads();  // all hs reads of this step done before overwrite

        if (k < Kx - 1) {
            #pragma unroll
            for (int st = 0; st < 2; ++st)
                #pragma unroll
                for (int dt = 0; dt < 2; ++dt) {
                    ushort4 shi, slo;
                    shi.x = rne16(hv[st][dt][0]);
                    shi.y = rne16(hv[st][dt][1]);
                    shi.z = rne16(hv[st][dt][2]);
                    shi.w = rne16(hv[st][dt][3]);
                    slo.x = rne16(hv[st][dt][0] - b2f(shi.x));
                    slo.y = rne16(hv[st][dt][1] - b2f(shi.y));
                    slo.z = rne16(hv[st][dt][2] - b2f(shi.z));
                    slo.w = rne16(hv[st][dt][3] - b2f(shi.w));
                    const int g16p = (v * 4 + dt * 2 + (quad >> 1)) ^ kk;
                    const int u4i = (st * 16 + row16) * 32 + g16p * 2 + (quad & 1);
                    ((ushort4*)hsHI)[u4i] = shi;
                    ((ushort4*)hsLO)[u4i] = slo;
                }
        } else {  // final step: park h as f32 for the epilogue (aliases hs)
            #pragma unroll
            for (int st = 0; st < 2; ++st)
                #pragma unroll
                for (int dt = 0; dt < 2; ++dt) {
                    float4 o4;
                    o4.x = hv[st][dt][0]; o4.y = hv[st][dt][1];
                    o4.z = hv[st][dt][2]; o4.w = hv[st][dt][3];
                    *(float4*)(hsF + (st * 16 + row16) * 136 + dimb + dt * 16
                               + quad * 4) = o4;
                }
        }
        __syncthreads();  // writes visible before next step's reads
    }

    // ---- epilogue: out = relu([S, h] @ W_comb^T + b_comb) ----
    const int dg = tid & 31;
    const int sg = tid >> 5;  // 0..7 -> seqs sg*4..+4
    float ac[4][4];
    #pragma unroll
    for (int i = 0; i < 4; ++i)
        #pragma unroll
        for (int j = 0; j < 4; ++j) ac[i][j] = 0.f;

    const float4* S4 = (const float4*)S;
    const float4* W4 = (const float4*)W_comb;
    #pragma unroll 4
    for (int d4 = 0; d4 < 32; ++d4) {
        float4 sv[4], wv[4];
        #pragma unroll
        for (int i = 0; i < 4; ++i)
            sv[i] = S4[(size_t)(m0 + sg * 4 + i) * 32 + d4];
        #pragma unroll
        for (int j = 0; j < 4; ++j) wv[j] = W4[(dg * 4 + j) * 64 + d4];
        #pragma unroll
        for (int i = 0; i < 4; ++i) {
            #pragma unroll
            for (int j = 0; j < 4; ++j) { FMA4(ac[i][j], sv[i], wv[j]); }
        }
    }
    #pragma unroll 4
    for (int d4 = 0; d4 < 32; ++d4) {
        float4 hvv[4], wv[4];
        #pragma unroll
        for (int i = 0; i < 4; ++i)
            hvv[i] = *(const float4*)(hsF + (sg * 4 + i) * 136 + d4 * 4);
        #pragma unroll
        for (int j = 0; j < 4; ++j) wv[j] = W4[(dg * 4 + j) * 64 + 32 + d4];
        #pragma unroll
        for (int i = 0; i < 4; ++i) {
            #pragma unroll
            for (int j = 0; j < 4; ++j) { FMA4(ac[i][j], hvv[i], wv[j]); }
        }
    }
    const float4 bc = ((const float4*)b_comb)[dg];
    #pragma unroll
    for (int i = 0; i < 4; ++i) {
        float4 o4;
        o4.x = fmaxf(ac[i][0] + bc.x, 0.f);
        o4.y = fmaxf(ac[i][1] + bc.y, 0.f);
        o4.z = fmaxf(ac[i][2] + bc.z, 0.f);
        o4.w = fmaxf(ac[i][3] + bc.w, 0.f);
        *(float4*)(out + (size_t)(m0 + sg * 4 + i) * 128 + dg * 4) = o4;
    }
}

extern "C" void kernel_launch(void* const* d_in, const int* in_sizes, int n_in,
                              void* d_out, int out_size, void* d_ws, size_t ws_size,
                              hipStream_t stream)
{
    const float* x      = (const float*)d_in[0];
    const int*   nidx   = (const int*)  d_in[1];
    const float* nw     = (const float*)d_in[2];
    const float* W_ih   = (const float*)d_in[3];
    const float* W_hh   = (const float*)d_in[4];
    const float* b_ih   = (const float*)d_in[5];
    const float* b_hh   = (const float*)d_in[6];
    const float* W_self = (const float*)d_in[7];
    const float* b_self = (const float*)d_in[8];
    const float* W_comb = (const float*)d_in[9];
    const float* b_comb = (const float*)d_in[10];
    float* out = (float*)d_out;

    float* G = (float*)d_ws;                         // 40000*512 f32 = 81.92 MB
    float* S = G + (size_t)Mx * G4x;                 // 40000*128 f32 = 20.48 MB
    unsigned short* WHp = (unsigned short*)(S + (size_t)Mx * Hx);  // 128 KB
    unsigned short* WLp = WHp + (size_t)G4x * Hx;                  // 128 KB
    float* bsum = (float*)(WLp + (size_t)G4x * Hx);                // 2 KB

    kw<<<(G4x * Hx + 255) / 256, 256, 0, stream>>>(W_hh, b_ih, b_hh, WHp, WLp, bsum);
    ka<<<Mx / 16, 128, 0, stream>>>(x, W_ih, W_self, b_self, G, S);
    kb<<<Mx / 32, 256, 0, stream>>>(G, S, WHp, WLp, bsum, nidx, nw,
                                    W_comb, b_comb, out);
}